// Round 6
// baseline (640.568 us; speedup 1.0000x reference)
//
#include <hip/hip_runtime.h>
#include <math.h>

#define N_NODES 100000
#define N_EDGES 600000
#define N_GRAPHS 512
#define D 128

typedef unsigned short u16;
typedef __attribute__((ext_vector_type(8))) short short8;
typedef __attribute__((ext_vector_type(4))) float f32x4;
typedef __attribute__((ext_vector_type(4))) unsigned int u32x4;

__device__ __forceinline__ u16 f2bf(float f) {
    unsigned int u = __float_as_uint(f);
    u += 0x7FFFu + ((u >> 16) & 1u);
    return (u16)(u >> 16);
}
__device__ __forceinline__ float bf2f(u16 h) {
    return __uint_as_float(((unsigned int)h) << 16);
}
// packed element: hi bf16 in top 16 bits, lo bf16 in low 16 bits
__device__ __forceinline__ unsigned int packsplit(float v) {
    unsigned int u = __float_as_uint(v);
    unsigned int hi = (u + (0x7FFFu + ((u >> 16) & 1u))) & 0xffff0000u;
    float lo = v - __uint_as_float(hi);
    unsigned int ul = __float_as_uint(lo);
    unsigned int l16 = (ul + (0x7FFFu + ((ul >> 16) & 1u))) >> 16;
    return hi | l16;
}
__device__ __forceinline__ float hi_f(unsigned int w) { return __uint_as_float(w & 0xffff0000u); }
__device__ __forceinline__ float lo_f(unsigned int w) { return __uint_as_float(w << 16); }
__device__ __forceinline__ float unpack_sum(unsigned int w) { return hi_f(w) + lo_f(w); }

// ---------------- zero helpers ----------------
__global__ __launch_bounds__(256) void zero_f_kernel(float* __restrict__ p, int n) {
    int i = blockIdx.x * 256 + threadIdx.x;
    if (i < n) p[i] = 0.0f;
}
__global__ __launch_bounds__(256) void zero_i_kernel(int* __restrict__ p, int n) {
    int i = blockIdx.x * 256 + threadIdx.x;
    if (i < n) p[i] = 0;
}

// ---------------- CSR build ----------------
__global__ __launch_bounds__(256) void hist_kernel(const int* __restrict__ dst,
                                                   int* __restrict__ deg) {
    int e = blockIdx.x * 256 + threadIdx.x;
    if (e < N_EDGES) atomicAdd(&deg[dst[e]], 1);
}

#define SCAN_BS 1024
__global__ __launch_bounds__(1024) void scan1_kernel(const int* __restrict__ deg,
                                                     int* __restrict__ excl,
                                                     int* __restrict__ blocksum) {
    __shared__ int buf[2][SCAN_BS];
    const int t = threadIdx.x;
    const int gid = blockIdx.x * SCAN_BS + t;
    int v = (gid < N_NODES) ? deg[gid] : 0;
    buf[0][t] = v;
    __syncthreads();
    int pi = 0;
    for (int off = 1; off < SCAN_BS; off <<= 1) {
        int val = buf[pi][t];
        if (t >= off) val += buf[pi][t - off];
        buf[pi ^ 1][t] = val;
        pi ^= 1;
        __syncthreads();
    }
    int incl = buf[pi][t];
    if (gid < N_NODES) excl[gid] = incl - v;
    if (t == SCAN_BS - 1) blocksum[blockIdx.x] = incl;
}

// parallel exclusive scan of block totals (<=128 elements), one block
__global__ __launch_bounds__(128) void scan2_kernel(int* __restrict__ blocksum, int n) {
    __shared__ int buf[2][128];
    const int t = threadIdx.x;
    int v = (t < n) ? blocksum[t] : 0;
    buf[0][t] = v;
    __syncthreads();
    int pi = 0;
    for (int off = 1; off < 128; off <<= 1) {
        int val = buf[pi][t];
        if (t >= off) val += buf[pi][t - off];
        buf[pi ^ 1][t] = val;
        pi ^= 1;
        __syncthreads();
    }
    if (t < n) blocksum[t] = buf[pi][t] - v;
}

__global__ __launch_bounds__(256) void scan3_kernel(const int* __restrict__ excl,
                                                    const int* __restrict__ blocksum,
                                                    int* __restrict__ rowptr) {
    int i = blockIdx.x * 256 + threadIdx.x;
    if (i < N_NODES) rowptr[i] = excl[i] + blocksum[i / SCAN_BS];
    if (i == 0) rowptr[N_NODES] = N_EDGES;
}

__global__ __launch_bounds__(256) void fill_kernel(const int* __restrict__ src,
                                                   const int* __restrict__ dst,
                                                   const int* __restrict__ rowptr,
                                                   int* __restrict__ fill,
                                                   int* __restrict__ csr_src) {
    int e = blockIdx.x * 256 + threadIdx.x;
    if (e < N_EDGES) {
        int d = dst[e];
        int pos = rowptr[d] + atomicAdd(&fill[d], 1);
        csr_src[pos] = src[e];
    }
}

// ---------------- split x (fp32 -> packed hi/lo u32) ----------------
__global__ __launch_bounds__(256) void split_x_kernel(const float* __restrict__ x,
                                                      unsigned int* __restrict__ Hx) {
    const int i = blockIdx.x * 256 + threadIdx.x;
    const float4 v = ((const float4*)x)[i];
    uint4 w;
    w.x = packsplit(v.x);
    w.y = packsplit(v.y);
    w.z = packsplit(v.z);
    w.w = packsplit(v.w);
    ((uint4*)Hx)[i] = w;
}

// ---------------- pack W' = [Wl ; Wr] (256x128) into MFMA B-fragment layout ----------------
// one launch, 3 layers x 64 tiles. tile t = nt*8+kt.
// Wp[(t*64+lane)*8+j] = W'[kt*32+(lane>>4)*8+j][nt*16+(lane&15)]
__global__ __launch_bounds__(64) void wprep_kernel(const float* __restrict__ Wl1, const float* __restrict__ Wr1,
                                                   const float* __restrict__ Wl2, const float* __restrict__ Wr2,
                                                   const float* __restrict__ Wl3, const float* __restrict__ Wr3,
                                                   u16* __restrict__ wph, u16* __restrict__ wpl) {
    const int layer = blockIdx.x >> 6;
    const int t = blockIdx.x & 63;
    const int lane = threadIdx.x;
    const float* Wl = (layer == 0) ? Wl1 : (layer == 1) ? Wl2 : Wl3;
    const float* Wr = (layer == 0) ? Wr1 : (layer == 1) ? Wr2 : Wr3;
    const int nt = t >> 3, kt = t & 7;
    const int n = nt * 16 + (lane & 15);
    const int k0 = kt * 32 + (lane >> 4) * 8;
    const size_t base = (size_t)layer * 32768 + (size_t)(t * 64 + lane) * 8;
    #pragma unroll
    for (int j = 0; j < 8; ++j) {
        const int k = k0 + j;
        const float w = (k < 128) ? Wl[k * 128 + n] : Wr[(k - 128) * 128 + n];
        const u16 h = f2bf(w);
        wph[base + j] = h;
        wpl[base + j] = f2bf(w - bf2f(h));
    }
}

// ---------------- aggregation: mean of neighbor rows (packed) ----------------
// one wave per node, lane covers 2 columns. csr indices loaded cooperatively,
// broadcast via shfl; 4 independent row loads in flight per iteration.
__global__ __launch_bounds__(256) void agg_kernel(const unsigned int* __restrict__ Hx,
                                                  const int* __restrict__ rowptr,
                                                  const int* __restrict__ csr_src,
                                                  unsigned int* __restrict__ Mx) {
    const int lane = threadIdx.x & 63;
    const int node = blockIdx.x * 4 + (threadIdx.x >> 6);
    if (node >= N_NODES) return;
    const int beg = rowptr[node];
    const int end = rowptr[node + 1];
    float a0 = 0.f, a1 = 0.f;
    const int co = lane * 2;
    for (int c0 = beg; c0 < end; c0 += 64) {
        const int nv = min(64, end - c0);
        int msrc = (c0 + lane < end) ? csr_src[c0 + lane] : 0;
        int j = 0;
        for (; j + 4 <= nv; j += 4) {
            const int s0 = __shfl(msrc, j + 0);
            const int s1 = __shfl(msrc, j + 1);
            const int s2 = __shfl(msrc, j + 2);
            const int s3 = __shfl(msrc, j + 3);
            const uint2 w0 = *(const uint2*)(Hx + (size_t)s0 * D + co);
            const uint2 w1 = *(const uint2*)(Hx + (size_t)s1 * D + co);
            const uint2 w2 = *(const uint2*)(Hx + (size_t)s2 * D + co);
            const uint2 w3 = *(const uint2*)(Hx + (size_t)s3 * D + co);
            a0 += unpack_sum(w0.x) + unpack_sum(w1.x) + unpack_sum(w2.x) + unpack_sum(w3.x);
            a1 += unpack_sum(w0.y) + unpack_sum(w1.y) + unpack_sum(w2.y) + unpack_sum(w3.y);
        }
        for (; j < nv; ++j) {
            const int s = __shfl(msrc, j);
            const uint2 w = *(const uint2*)(Hx + (size_t)s * D + co);
            a0 += unpack_sum(w.x);
            a1 += unpack_sum(w.y);
        }
    }
    const float inv = 1.0f / (float)max(end - beg, 1);
    uint2 o;
    o.x = packsplit(a0 * inv);
    o.y = packsplit(a1 * inv);
    *(uint2*)(Mx + (size_t)node * D + co) = o;
}

// ---------------- MFMA GEMM: h' = relu([M | H] @ [Wl;Wr] + b) ----------------
// 128 rows/block = 4 waves x 32 rows (2 A-sets of 16). kt-outer loop with all
// accumulators resident; per kt the wave issues 16 independent B-loads then
// 48 MFMAs (3:1 MFMA:load). bf16x3 emulation. h' written packed in place over
// Hx (per-wave read-before-write of its own rows only: race-free).
__global__ __launch_bounds__(256) void gemm_kernel(const unsigned int* __restrict__ Mx,
                                                   const unsigned int* Hx,
                                                   const u16* __restrict__ Wph,
                                                   const u16* __restrict__ Wpl,
                                                   const float* __restrict__ bias,
                                                   unsigned int* OHx) {
    const int lane = threadIdx.x & 63;
    const int wv = threadIdx.x >> 6;
    const int m0 = blockIdx.x * 128 + wv * 32;
    const int ko = (lane >> 4) * 8;

    int rmA[2];
    #pragma unroll
    for (int s = 0; s < 2; ++s) {
        int r = m0 + s * 16 + (lane & 15);
        rmA[s] = (r < N_NODES) ? r : 0;
    }

    f32x4 accP[2][8], accQ[2][8];
    #pragma unroll
    for (int s = 0; s < 2; ++s)
        #pragma unroll
        for (int nt = 0; nt < 8; ++nt) {
            accP[s][nt] = (f32x4){0.f, 0.f, 0.f, 0.f};
            accQ[s][nt] = (f32x4){0.f, 0.f, 0.f, 0.f};
        }

    #pragma unroll
    for (int kt = 0; kt < 8; ++kt) {
        // A fragments for this kt (per row-set): Mx for kt<4, Hx for kt>=4
        short8 ah[2], al[2];
        #pragma unroll
        for (int s = 0; s < 2; ++s) {
            const unsigned int* base = (kt < 4)
                ? (Mx + (size_t)rmA[s] * D + kt * 32 + ko)
                : (Hx + (size_t)rmA[s] * D + (kt - 4) * 32 + ko);
            const u32x4 p = *(const u32x4*)(base);
            const u32x4 q = *(const u32x4*)(base + 4);
            u32x4 hv, lv;
            hv.x = (p.x >> 16) | (p.y & 0xffff0000u);
            hv.y = (p.z >> 16) | (p.w & 0xffff0000u);
            hv.z = (q.x >> 16) | (q.y & 0xffff0000u);
            hv.w = (q.z >> 16) | (q.w & 0xffff0000u);
            lv.x = (p.x & 0xffffu) | (p.y << 16);
            lv.y = (p.z & 0xffffu) | (p.w << 16);
            lv.z = (q.x & 0xffffu) | (q.y << 16);
            lv.w = (q.z & 0xffffu) | (q.w << 16);
            ah[s] = __builtin_bit_cast(short8, hv);
            al[s] = __builtin_bit_cast(short8, lv);
        }
        // all B fragments for this kt (8 nt x hi/lo), batched independent loads
        short8 bh[8], bl[8];
        #pragma unroll
        for (int nt = 0; nt < 8; ++nt) {
            bh[nt] = *(const short8*)(Wph + (size_t)((nt * 8 + kt) * 64 + lane) * 8);
            bl[nt] = *(const short8*)(Wpl + (size_t)((nt * 8 + kt) * 64 + lane) * 8);
        }
        #pragma unroll
        for (int nt = 0; nt < 8; ++nt) {
            #pragma unroll
            for (int s = 0; s < 2; ++s) {
                accP[s][nt] = __builtin_amdgcn_mfma_f32_16x16x32_bf16(ah[s], bh[nt], accP[s][nt], 0, 0, 0);
                accQ[s][nt] = __builtin_amdgcn_mfma_f32_16x16x32_bf16(al[s], bh[nt], accQ[s][nt], 0, 0, 0);
                accQ[s][nt] = __builtin_amdgcn_mfma_f32_16x16x32_bf16(ah[s], bl[nt], accQ[s][nt], 0, 0, 0);
            }
        }
    }

    const int cl = lane & 15;
    #pragma unroll
    for (int s = 0; s < 2; ++s) {
        const int rowb = m0 + s * 16 + ((lane >> 4) << 2);
        #pragma unroll
        for (int nt = 0; nt < 8; ++nt) {
            const int col = nt * 16 + cl;
            const float bv = bias[col];
            #pragma unroll
            for (int r = 0; r < 4; ++r) {
                const int row = rowb + r;
                if (row < N_NODES) {
                    const float v = fmaxf(accP[s][nt][r] + accQ[s][nt][r] + bv, 0.f);
                    OHx[(size_t)row * D + col] = packsplit(v);
                }
            }
        }
    }
}

// ---------------- per-graph sum pooling from packed h (batch sorted) ----------------
#define PNODES 32
__global__ __launch_bounds__(128) void pool_kernel(const unsigned int* __restrict__ Hx,
                                                   const int* __restrict__ batch,
                                                   float* __restrict__ pooled) {
    const int c = threadIdx.x;
    const int base = blockIdx.x * PNODES;
    int cur = -1;
    float acc = 0.0f;
    for (int i = 0; i < PNODES; ++i) {
        int node = base + i;
        if (node >= N_NODES) break;
        int g = batch[node];
        if (g != cur) {
            if (cur >= 0) atomicAdd(&pooled[(size_t)cur * D + c], acc);
            cur = g;
            acc = 0.0f;
        }
        acc += unpack_sum(Hx[(size_t)node * D + c]);
    }
    if (cur >= 0) atomicAdd(&pooled[(size_t)cur * D + c], acc);
}

// ---------------- readout: sigmoid(pooled @ Wro + bro) ----------------
__global__ __launch_bounds__(128) void final_kernel(const float* __restrict__ pooled,
                                                    const float* __restrict__ Wro,
                                                    const float* __restrict__ bro,
                                                    float* __restrict__ out) {
    const int g = blockIdx.x;
    const int c = threadIdx.x;
    float v = pooled[(size_t)g * D + c] * Wro[c];
    #pragma unroll
    for (int off = 32; off > 0; off >>= 1) v += __shfl_down(v, off, 64);
    __shared__ float partial[2];
    if ((c & 63) == 0) partial[c >> 6] = v;
    __syncthreads();
    if (c == 0) {
        float s = partial[0] + partial[1] + bro[0];
        out[g] = 1.0f / (1.0f + expf(-s));
    }
}

extern "C" void kernel_launch(void* const* d_in, const int* in_sizes, int n_in,
                              void* d_out, int out_size, void* d_ws, size_t ws_size,
                              hipStream_t stream) {
    const float* x     = (const float*)d_in[0];
    const int*   ei    = (const int*)d_in[1];
    const int*   batch = (const int*)d_in[2];
    const int*   src   = ei;
    const int*   dst   = ei + N_EDGES;
    const float* Wl[3] = {(const float*)d_in[3], (const float*)d_in[6], (const float*)d_in[9]};
    const float* Wr[3] = {(const float*)d_in[4], (const float*)d_in[7], (const float*)d_in[10]};
    const float* bs[3] = {(const float*)d_in[5], (const float*)d_in[8], (const float*)d_in[11]};
    const float* Wro   = (const float*)d_in[12];
    const float* bro   = (const float*)d_in[13];
    float* out = (float*)d_out;

    const size_t ND = (size_t)N_NODES * D;
    char* ws = (char*)d_ws;
    unsigned int* Hx = (unsigned int*)ws;          // ND u32 (packed hi/lo)
    unsigned int* Mx = Hx + ND;                    // ND u32
    float* pooled = (float*)(Mx + ND);             // G*D f32
    u16* Wph = (u16*)(pooled + (size_t)N_GRAPHS * D);  // 3*32768 u16
    u16* Wpl = Wph + 3 * 32768;                        // 3*32768 u16
    int* deg      = (int*)(Wpl + 3 * 32768);       // N (deg, fill adjacent for fused zero)
    int* fill     = deg + N_NODES;                 // N
    int* excl     = fill + N_NODES;                // N
    int* blocksum = excl + N_NODES;                // 128
    int* rowptr   = blocksum + 128;                // N+1
    int* csr_src  = rowptr + N_NODES + 1;          // E

    const int EB      = (N_EDGES + 255) / 256;
    const int NB      = (N_NODES + 255) / 256;
    const int NB2     = (2 * N_NODES + 255) / 256;
    const int SCAN_NB = (N_NODES + SCAN_BS - 1) / SCAN_BS;   // 98
    const int ZB_P    = (N_GRAPHS * D + 255) / 256;
    const int SPLIT_B = (int)(ND / 4 / 256);                 // 12500
    const int AGG_B   = N_NODES / 4;                         // 25000
    const int GEMM_B  = (N_NODES + 127) / 128;               // 782
    const int POOL_B  = N_NODES / PNODES;                    // 3125

    // ---- CSR build ----
    zero_i_kernel<<<NB2, 256, 0, stream>>>(deg, 2 * N_NODES);   // deg + fill
    hist_kernel<<<EB, 256, 0, stream>>>(dst, deg);
    scan1_kernel<<<SCAN_NB, SCAN_BS, 0, stream>>>(deg, excl, blocksum);
    scan2_kernel<<<1, 128, 0, stream>>>(blocksum, SCAN_NB);
    scan3_kernel<<<NB, 256, 0, stream>>>(excl, blocksum, rowptr);
    fill_kernel<<<EB, 256, 0, stream>>>(src, dst, rowptr, fill, csr_src);

    // ---- prep: split x, pack weights (single launch) ----
    split_x_kernel<<<SPLIT_B, 256, 0, stream>>>(x, Hx);
    wprep_kernel<<<192, 64, 0, stream>>>(Wl[0], Wr[0], Wl[1], Wr[1], Wl[2], Wr[2], Wph, Wpl);

    // ---- 3 layers: aggregate-then-GEMM (h packed, updated in place) ----
    for (int l = 0; l < 3; ++l) {
        agg_kernel<<<AGG_B, 256, 0, stream>>>(Hx, rowptr, csr_src, Mx);
        gemm_kernel<<<GEMM_B, 256, 0, stream>>>(Mx, Hx,
                                                Wph + l * 32768, Wpl + l * 32768, bs[l],
                                                Hx);
    }

    // ---- pooling + readout ----
    zero_f_kernel<<<ZB_P, 256, 0, stream>>>(pooled, N_GRAPHS * D);
    pool_kernel<<<POOL_B, 128, 0, stream>>>(Hx, batch, pooled);
    final_kernel<<<N_GRAPHS, 128, 0, stream>>>(pooled, Wro, bro, out);
}

// Round 7
// 482.427 us; speedup vs baseline: 1.3278x; 1.3278x over previous
//
#include <hip/hip_runtime.h>
#include <math.h>

#define N_NODES 100000
#define N_EDGES 600000
#define N_GRAPHS 512
#define D 128

typedef unsigned short u16;
typedef __attribute__((ext_vector_type(8))) short short8;
typedef __attribute__((ext_vector_type(4))) float f32x4;
typedef __attribute__((ext_vector_type(4))) unsigned int u32x4;

__device__ __forceinline__ u16 f2bf(float f) {
    unsigned int u = __float_as_uint(f);
    u += 0x7FFFu + ((u >> 16) & 1u);
    return (u16)(u >> 16);
}
__device__ __forceinline__ float bf2f(u16 h) {
    return __uint_as_float(((unsigned int)h) << 16);
}
// packed element: hi bf16 in top 16 bits, lo bf16 in low 16 bits
__device__ __forceinline__ unsigned int packsplit(float v) {
    unsigned int u = __float_as_uint(v);
    unsigned int hi = (u + (0x7FFFu + ((u >> 16) & 1u))) & 0xffff0000u;
    float lo = v - __uint_as_float(hi);
    unsigned int ul = __float_as_uint(lo);
    unsigned int l16 = (ul + (0x7FFFu + ((ul >> 16) & 1u))) >> 16;
    return hi | l16;
}
__device__ __forceinline__ float hi_f(unsigned int w) { return __uint_as_float(w & 0xffff0000u); }
__device__ __forceinline__ float lo_f(unsigned int w) { return __uint_as_float(w << 16); }
__device__ __forceinline__ float unpack_sum(unsigned int w) { return hi_f(w) + lo_f(w); }

// ---------------- zero helpers ----------------
__global__ __launch_bounds__(256) void zero_f_kernel(float* __restrict__ p, int n) {
    int i = blockIdx.x * 256 + threadIdx.x;
    if (i < n) p[i] = 0.0f;
}
__global__ __launch_bounds__(256) void zero_i_kernel(int* __restrict__ p, int n) {
    int i = blockIdx.x * 256 + threadIdx.x;
    if (i < n) p[i] = 0;
}

// ---------------- CSR build ----------------
__global__ __launch_bounds__(256) void hist_kernel(const int* __restrict__ dst,
                                                   int* __restrict__ deg) {
    int e = blockIdx.x * 256 + threadIdx.x;
    if (e < N_EDGES) atomicAdd(&deg[dst[e]], 1);
}

#define SCAN_BS 1024
__global__ __launch_bounds__(1024) void scan1_kernel(const int* __restrict__ deg,
                                                     int* __restrict__ excl,
                                                     int* __restrict__ blocksum) {
    __shared__ int buf[2][SCAN_BS];
    const int t = threadIdx.x;
    const int gid = blockIdx.x * SCAN_BS + t;
    int v = (gid < N_NODES) ? deg[gid] : 0;
    buf[0][t] = v;
    __syncthreads();
    int pi = 0;
    for (int off = 1; off < SCAN_BS; off <<= 1) {
        int val = buf[pi][t];
        if (t >= off) val += buf[pi][t - off];
        buf[pi ^ 1][t] = val;
        pi ^= 1;
        __syncthreads();
    }
    int incl = buf[pi][t];
    if (gid < N_NODES) excl[gid] = incl - v;
    if (t == SCAN_BS - 1) blocksum[blockIdx.x] = incl;
}

// parallel exclusive scan of block totals (<=128 elements), one block
__global__ __launch_bounds__(128) void scan2_kernel(int* __restrict__ blocksum, int n) {
    __shared__ int buf[2][128];
    const int t = threadIdx.x;
    int v = (t < n) ? blocksum[t] : 0;
    buf[0][t] = v;
    __syncthreads();
    int pi = 0;
    for (int off = 1; off < 128; off <<= 1) {
        int val = buf[pi][t];
        if (t >= off) val += buf[pi][t - off];
        buf[pi ^ 1][t] = val;
        pi ^= 1;
        __syncthreads();
    }
    if (t < n) blocksum[t] = buf[pi][t] - v;
}

__global__ __launch_bounds__(256) void scan3_kernel(const int* __restrict__ excl,
                                                    const int* __restrict__ blocksum,
                                                    int* __restrict__ rowptr) {
    int i = blockIdx.x * 256 + threadIdx.x;
    if (i < N_NODES) rowptr[i] = excl[i] + blocksum[i / SCAN_BS];
    if (i == 0) rowptr[N_NODES] = N_EDGES;
}

__global__ __launch_bounds__(256) void fill_kernel(const int* __restrict__ src,
                                                   const int* __restrict__ dst,
                                                   const int* __restrict__ rowptr,
                                                   int* __restrict__ fill,
                                                   int* __restrict__ csr_src) {
    int e = blockIdx.x * 256 + threadIdx.x;
    if (e < N_EDGES) {
        int d = dst[e];
        int pos = rowptr[d] + atomicAdd(&fill[d], 1);
        csr_src[pos] = src[e];
    }
}

// ---------------- split x (fp32 -> packed hi/lo u32) ----------------
__global__ __launch_bounds__(256) void split_x_kernel(const float* __restrict__ x,
                                                      unsigned int* __restrict__ Hx) {
    const int i = blockIdx.x * 256 + threadIdx.x;
    const float4 v = ((const float4*)x)[i];
    uint4 w;
    w.x = packsplit(v.x);
    w.y = packsplit(v.y);
    w.z = packsplit(v.z);
    w.w = packsplit(v.w);
    ((uint4*)Hx)[i] = w;
}

// ---------------- pack W' = [Wl ; Wr] (256x128) into MFMA B-fragment layout ----------------
// one launch, 3 layers x 64 tiles. tile t = nt*8+kt.
// Wp[(t*64+lane)*8+j] = W'[kt*32+(lane>>4)*8+j][nt*16+(lane&15)]
__global__ __launch_bounds__(64) void wprep_kernel(const float* __restrict__ Wl1, const float* __restrict__ Wr1,
                                                   const float* __restrict__ Wl2, const float* __restrict__ Wr2,
                                                   const float* __restrict__ Wl3, const float* __restrict__ Wr3,
                                                   u16* __restrict__ wph, u16* __restrict__ wpl) {
    const int layer = blockIdx.x >> 6;
    const int t = blockIdx.x & 63;
    const int lane = threadIdx.x;
    const float* Wl = (layer == 0) ? Wl1 : (layer == 1) ? Wl2 : Wl3;
    const float* Wr = (layer == 0) ? Wr1 : (layer == 1) ? Wr2 : Wr3;
    const int nt = t >> 3, kt = t & 7;
    const int n = nt * 16 + (lane & 15);
    const int k0 = kt * 32 + (lane >> 4) * 8;
    const size_t base = (size_t)layer * 32768 + (size_t)(t * 64 + lane) * 8;
    #pragma unroll
    for (int j = 0; j < 8; ++j) {
        const int k = k0 + j;
        const float w = (k < 128) ? Wl[k * 128 + n] : Wr[(k - 128) * 128 + n];
        const u16 h = f2bf(w);
        wph[base + j] = h;
        wpl[base + j] = f2bf(w - bf2f(h));
    }
}

// ---------------- aggregation: mean of neighbor rows (packed) ----------------
// one wave per node, lane covers 2 columns. csr indices loaded cooperatively,
// broadcast via shfl; 4 independent row loads in flight per iteration.
__global__ __launch_bounds__(256) void agg_kernel(const unsigned int* __restrict__ Hx,
                                                  const int* __restrict__ rowptr,
                                                  const int* __restrict__ csr_src,
                                                  unsigned int* __restrict__ Mx) {
    const int lane = threadIdx.x & 63;
    const int node = blockIdx.x * 4 + (threadIdx.x >> 6);
    if (node >= N_NODES) return;
    const int beg = rowptr[node];
    const int end = rowptr[node + 1];
    float a0 = 0.f, a1 = 0.f;
    const int co = lane * 2;
    for (int c0 = beg; c0 < end; c0 += 64) {
        const int nv = min(64, end - c0);
        int msrc = (c0 + lane < end) ? csr_src[c0 + lane] : 0;
        int j = 0;
        for (; j + 4 <= nv; j += 4) {
            const int s0 = __shfl(msrc, j + 0);
            const int s1 = __shfl(msrc, j + 1);
            const int s2 = __shfl(msrc, j + 2);
            const int s3 = __shfl(msrc, j + 3);
            const uint2 w0 = *(const uint2*)(Hx + (size_t)s0 * D + co);
            const uint2 w1 = *(const uint2*)(Hx + (size_t)s1 * D + co);
            const uint2 w2 = *(const uint2*)(Hx + (size_t)s2 * D + co);
            const uint2 w3 = *(const uint2*)(Hx + (size_t)s3 * D + co);
            a0 += unpack_sum(w0.x) + unpack_sum(w1.x) + unpack_sum(w2.x) + unpack_sum(w3.x);
            a1 += unpack_sum(w0.y) + unpack_sum(w1.y) + unpack_sum(w2.y) + unpack_sum(w3.y);
        }
        for (; j < nv; ++j) {
            const int s = __shfl(msrc, j);
            const uint2 w = *(const uint2*)(Hx + (size_t)s * D + co);
            a0 += unpack_sum(w.x);
            a1 += unpack_sum(w.y);
        }
    }
    const float inv = 1.0f / (float)max(end - beg, 1);
    uint2 o;
    o.x = packsplit(a0 * inv);
    o.y = packsplit(a1 * inv);
    *(uint2*)(Mx + (size_t)node * D + co) = o;
}

// ---------------- MFMA GEMM: h' = relu([M | H] @ [Wl;Wr] + b) ----------------
// 64 rows/block (4 waves x 16), N=128, K=256, bf16x3 emulation.
// W fragments staged per nt-pair into 32 KB LDS (one global copy per block,
// shared by 4 waves); B read via ds_read_b128. 8 live acc regs per wave
// (nt-outer), so VGPR stays ~110 -> 4 waves/SIMD.
__global__ __launch_bounds__(256, 4) void gemm_kernel(const unsigned int* __restrict__ Mx,
                                                      const unsigned int* Hx,
                                                      const u16* __restrict__ Wph,
                                                      const u16* __restrict__ Wpl,
                                                      const float* __restrict__ bias,
                                                      unsigned int* OHx) {
    __shared__ uint4 ldsW[2048];   // 32 KB: [0:1024) = Wph nt-pair, [1024:2048) = Wpl nt-pair
    const int lane = threadIdx.x & 63;
    const int wv = threadIdx.x >> 6;
    const int m0 = blockIdx.x * 64 + wv * 16;
    int rm = m0 + (lane & 15);
    if (rm >= N_NODES) rm = 0;
    const int ko = (lane >> 4) * 8;

    // A fragments once (16 rows/wave): kt<4 from Mx (mean), kt>=4 from Hx (root)
    short8 ah[8], al[8];
    #pragma unroll
    for (int kt = 0; kt < 4; ++kt) {
        #pragma unroll
        for (int half = 0; half < 2; ++half) {
            const unsigned int* base = (half == 0) ? (Mx + (size_t)rm * D + kt * 32 + ko)
                                                   : (Hx + (size_t)rm * D + kt * 32 + ko);
            const u32x4 p = *(const u32x4*)(base);
            const u32x4 q = *(const u32x4*)(base + 4);
            u32x4 hv, lv;
            hv.x = (p.x >> 16) | (p.y & 0xffff0000u);
            hv.y = (p.z >> 16) | (p.w & 0xffff0000u);
            hv.z = (q.x >> 16) | (q.y & 0xffff0000u);
            hv.w = (q.z >> 16) | (q.w & 0xffff0000u);
            lv.x = (p.x & 0xffffu) | (p.y << 16);
            lv.y = (p.z & 0xffffu) | (p.w << 16);
            lv.z = (q.x & 0xffffu) | (q.y << 16);
            lv.w = (q.z & 0xffffu) | (q.w << 16);
            ah[half * 4 + kt] = __builtin_bit_cast(short8, hv);
            al[half * 4 + kt] = __builtin_bit_cast(short8, lv);
        }
    }

    const int rowb = m0 + ((lane >> 4) << 2);
    const int cl = lane & 15;
    const int t = threadIdx.x;
    const u16* ldsU = (const u16*)ldsW;

    #pragma unroll
    for (int ntc = 0; ntc < 4; ++ntc) {
        // stage W fragments for nt = 2*ntc, 2*ntc+1 (16 KB hi + 16 KB lo)
        __syncthreads();   // previous chunk's reads done
        {
            const uint4* gh = (const uint4*)(Wph + (size_t)(2 * ntc) * 4096);
            const uint4* gl = (const uint4*)(Wpl + (size_t)(2 * ntc) * 4096);
            #pragma unroll
            for (int i = 0; i < 4; ++i) {
                ldsW[t + 256 * i]        = gh[t + 256 * i];
                ldsW[1024 + t + 256 * i] = gl[t + 256 * i];
            }
        }
        __syncthreads();

        #pragma unroll
        for (int nt2 = 0; nt2 < 2; ++nt2) {
            f32x4 accP = {0.f, 0.f, 0.f, 0.f};
            f32x4 accQ = {0.f, 0.f, 0.f, 0.f};
            #pragma unroll
            for (int kt = 0; kt < 8; ++kt) {
                const int fo = (nt2 * 8 + kt) * 512 + lane * 8;
                const short8 bh = *(const short8*)(ldsU + fo);
                const short8 bl = *(const short8*)(ldsU + 8192 + fo);
                accP = __builtin_amdgcn_mfma_f32_16x16x32_bf16(ah[kt], bh, accP, 0, 0, 0);
                accQ = __builtin_amdgcn_mfma_f32_16x16x32_bf16(al[kt], bh, accQ, 0, 0, 0);
                accQ = __builtin_amdgcn_mfma_f32_16x16x32_bf16(ah[kt], bl, accQ, 0, 0, 0);
            }
            const int col = (ntc * 2 + nt2) * 16 + cl;
            const float bv = bias[col];
            #pragma unroll
            for (int r = 0; r < 4; ++r) {
                const int row = rowb + r;
                if (row < N_NODES) {
                    const float v = fmaxf(accP[r] + accQ[r] + bv, 0.f);
                    OHx[(size_t)row * D + col] = packsplit(v);
                }
            }
        }
    }
}

// ---------------- per-graph sum pooling from packed h (batch sorted) ----------------
#define PNODES 32
__global__ __launch_bounds__(128) void pool_kernel(const unsigned int* __restrict__ Hx,
                                                   const int* __restrict__ batch,
                                                   float* __restrict__ pooled) {
    const int c = threadIdx.x;
    const int base = blockIdx.x * PNODES;
    int cur = -1;
    float acc = 0.0f;
    for (int i = 0; i < PNODES; ++i) {
        int node = base + i;
        if (node >= N_NODES) break;
        int g = batch[node];
        if (g != cur) {
            if (cur >= 0) atomicAdd(&pooled[(size_t)cur * D + c], acc);
            cur = g;
            acc = 0.0f;
        }
        acc += unpack_sum(Hx[(size_t)node * D + c]);
    }
    if (cur >= 0) atomicAdd(&pooled[(size_t)cur * D + c], acc);
}

// ---------------- readout: sigmoid(pooled @ Wro + bro) ----------------
__global__ __launch_bounds__(128) void final_kernel(const float* __restrict__ pooled,
                                                    const float* __restrict__ Wro,
                                                    const float* __restrict__ bro,
                                                    float* __restrict__ out) {
    const int g = blockIdx.x;
    const int c = threadIdx.x;
    float v = pooled[(size_t)g * D + c] * Wro[c];
    #pragma unroll
    for (int off = 32; off > 0; off >>= 1) v += __shfl_down(v, off, 64);
    __shared__ float partial[2];
    if ((c & 63) == 0) partial[c >> 6] = v;
    __syncthreads();
    if (c == 0) {
        float s = partial[0] + partial[1] + bro[0];
        out[g] = 1.0f / (1.0f + expf(-s));
    }
}

extern "C" void kernel_launch(void* const* d_in, const int* in_sizes, int n_in,
                              void* d_out, int out_size, void* d_ws, size_t ws_size,
                              hipStream_t stream) {
    const float* x     = (const float*)d_in[0];
    const int*   ei    = (const int*)d_in[1];
    const int*   batch = (const int*)d_in[2];
    const int*   src   = ei;
    const int*   dst   = ei + N_EDGES;
    const float* Wl[3] = {(const float*)d_in[3], (const float*)d_in[6], (const float*)d_in[9]};
    const float* Wr[3] = {(const float*)d_in[4], (const float*)d_in[7], (const float*)d_in[10]};
    const float* bs[3] = {(const float*)d_in[5], (const float*)d_in[8], (const float*)d_in[11]};
    const float* Wro   = (const float*)d_in[12];
    const float* bro   = (const float*)d_in[13];
    float* out = (float*)d_out;

    const size_t ND = (size_t)N_NODES * D;
    char* ws = (char*)d_ws;
    unsigned int* Hx = (unsigned int*)ws;          // ND u32 (packed hi/lo)
    unsigned int* Mx = Hx + ND;                    // ND u32
    float* pooled = (float*)(Mx + ND);             // G*D f32
    u16* Wph = (u16*)(pooled + (size_t)N_GRAPHS * D);  // 3*32768 u16
    u16* Wpl = Wph + 3 * 32768;                        // 3*32768 u16
    int* deg      = (int*)(Wpl + 3 * 32768);       // N (deg, fill adjacent for fused zero)
    int* fill     = deg + N_NODES;                 // N
    int* excl     = fill + N_NODES;                // N
    int* blocksum = excl + N_NODES;                // 128
    int* rowptr   = blocksum + 128;                // N+1
    int* csr_src  = rowptr + N_NODES + 1;          // E

    const int EB      = (N_EDGES + 255) / 256;
    const int NB      = (N_NODES + 255) / 256;
    const int NB2     = (2 * N_NODES + 255) / 256;
    const int SCAN_NB = (N_NODES + SCAN_BS - 1) / SCAN_BS;   // 98
    const int ZB_P    = (N_GRAPHS * D + 255) / 256;
    const int SPLIT_B = (int)(ND / 4 / 256);                 // 12500
    const int AGG_B   = N_NODES / 4;                         // 25000
    const int GEMM_B  = (N_NODES + 63) / 64;                 // 1563
    const int POOL_B  = N_NODES / PNODES;                    // 3125

    // ---- CSR build ----
    zero_i_kernel<<<NB2, 256, 0, stream>>>(deg, 2 * N_NODES);   // deg + fill
    hist_kernel<<<EB, 256, 0, stream>>>(dst, deg);
    scan1_kernel<<<SCAN_NB, SCAN_BS, 0, stream>>>(deg, excl, blocksum);
    scan2_kernel<<<1, 128, 0, stream>>>(blocksum, SCAN_NB);
    scan3_kernel<<<NB, 256, 0, stream>>>(excl, blocksum, rowptr);
    fill_kernel<<<EB, 256, 0, stream>>>(src, dst, rowptr, fill, csr_src);

    // ---- prep: split x, pack weights (single launch) ----
    split_x_kernel<<<SPLIT_B, 256, 0, stream>>>(x, Hx);
    wprep_kernel<<<192, 64, 0, stream>>>(Wl[0], Wr[0], Wl[1], Wr[1], Wl[2], Wr[2], Wph, Wpl);

    // ---- 3 layers: aggregate-then-GEMM (h packed, updated in place) ----
    for (int l = 0; l < 3; ++l) {
        agg_kernel<<<AGG_B, 256, 0, stream>>>(Hx, rowptr, csr_src, Mx);
        gemm_kernel<<<GEMM_B, 256, 0, stream>>>(Mx, Hx,
                                                Wph + l * 32768, Wpl + l * 32768, bs[l],
                                                Hx);
    }

    // ---- pooling + readout ----
    zero_f_kernel<<<ZB_P, 256, 0, stream>>>(pooled, N_GRAPHS * D);
    pool_kernel<<<POOL_B, 128, 0, stream>>>(Hx, batch, pooled);
    final_kernel<<<N_GRAPHS, 128, 0, stream>>>(pooled, Wro, bro, out);
}